// Round 13
// baseline (1003.815 us; speedup 1.0000x reference)
//
#include <hip/hip_runtime.h>

typedef short bf16x8 __attribute__((ext_vector_type(8)));
typedef float f32x4  __attribute__((ext_vector_type(4)));

#define TSTEPS 1000
#define BATCH  512
#define HID    64
#define INPD   64
#define FEAT   128
#define KEEP   5
#define KH     320
#define ALPHA  0.2f
#define BB     2
#define NBLK   (BATCH/BB)   // 256
#define NTHR   512

#define MFMA(a,b,c) __builtin_amdgcn_mfma_f32_16x16x32_bf16(a, b, c, 0, 0, 0)

template<int P> struct IC { static constexpr int v = P; };

// Raw barrier: flush own LDS writes, sync. No vmcnt drain.
__device__ __forceinline__ void barrier_fast() {
  asm volatile("s_waitcnt lgkmcnt(0)" ::: "memory");
  __builtin_amdgcn_s_barrier();
  asm volatile("" ::: "memory");
}

// lane <-> lane^2 exchange via DPP quad_perm [2,3,0,1] (VALU, not LDS pipe)
__device__ __forceinline__ float qx2(float v) {
  return __uint_as_float((unsigned)__builtin_amdgcn_update_dpp(
      0, (int)__float_as_uint(v), 0x4E /*quad_perm[2,3,0,1]*/, 0xF, 0xF, true));
}
// hi/lo column fold: cols (0,1)=hi products, (2,3)=lo products; total = v + v[lane^2]
__device__ __forceinline__ f32x4 fold2(f32x4 v) {
  f32x4 r;
  r.x = v.x + qx2(v.x);
  r.y = v.y + qx2(v.y);
  r.z = v.z + qx2(v.z);
  r.w = v.w + qx2(v.w);
  return r;
}

// split 4 f32 into bf16-hi (truncated) and bf16-lo (rounded residual), packed 2-per-u32
__device__ __forceinline__ void pack4(float x0, float x1, float x2, float x3,
                                      unsigned &h0, unsigned &h1,
                                      unsigned &l0, unsigned &l1) {
  unsigned a0 = __float_as_uint(x0), a1 = __float_as_uint(x1);
  unsigned a2 = __float_as_uint(x2), a3 = __float_as_uint(x3);
  h0 = __builtin_amdgcn_perm(a1, a0, 0x07060302u);
  h1 = __builtin_amdgcn_perm(a3, a2, 0x07060302u);
  float r0 = x0 - __uint_as_float(a0 & 0xFFFF0000u);
  float r1 = x1 - __uint_as_float(a1 & 0xFFFF0000u);
  float r2 = x2 - __uint_as_float(a2 & 0xFFFF0000u);
  float r3 = x3 - __uint_as_float(a3 & 0xFFFF0000u);
  asm("v_cvt_pk_bf16_f32 %0, %1, %2" : "=v"(l0) : "v"(r0), "v"(r1));
  asm("v_cvt_pk_bf16_f32 %0, %1, %2" : "=v"(l1) : "v"(r2), "v"(r3));
}

__device__ __forceinline__ void pack_frag(float4 v0, float4 v1, bf16x8 &hi, bf16x8 &lo) {
  int4 h4, l4;
  pack4(v0.x, v0.y, v0.z, v0.w, (unsigned&)h4.x, (unsigned&)h4.y, (unsigned&)l4.x, (unsigned&)l4.y);
  pack4(v1.x, v1.y, v1.z, v1.w, (unsigned&)h4.z, (unsigned&)h4.w, (unsigned&)l4.z, (unsigned&)l4.w);
  hi = __builtin_bit_cast(bf16x8, h4);
  lo = __builtin_bit_cast(bf16x8, l4);
}

__device__ __forceinline__ void load_wfrag(const float* p, bf16x8 &hi, bf16x8 &lo) {
  float4 v0 = *(const float4*)p;
  float4 v1 = *(const float4*)(p + 4);
  pack_frag(v0, v1, hi, lo);
}

// ---------------- packed-column MFMA kernel, balanced 2-phase, DPP folds ----------------
// Carried MLP1 acc spans phases: P1(t-1) adds r2,r3; P2(t-1) adds r0,r1; P1(t) adds newest.
// P1 (all): read h-frag; publish a(t) (newest pair, split chain); gA: RNN+hobs;
//           start acc(t+1) with r2,r3.                                         bar A
// P2: gA: acc(t+1) += r0,r1; MLP2 (2x2-deep); hn = mix(hobs,hm); io; stage B1lds
//     gB: acc(t+1) += r0,r1; issue x[t+2]; pack x[t+1]; XIN -> xin_s[(t+1)&1]  bar B
__global__ __launch_bounds__(NTHR, 2) void seq_kernel(
    const float* __restrict__ x,    float* __restrict__ io,
    const float* __restrict__ h0g,
    const float* __restrict__ W_in, const float* __restrict__ b_in,
    const float* __restrict__ W_hh, const float* __restrict__ b_hh,
    const float* __restrict__ W1,   const float* __restrict__ b1,
    const float* __restrict__ W2,   const float* __restrict__ b2) {

  __shared__ __align__(16) short B1lds[1024];
  __shared__ __align__(16) short a_s[512];
  __shared__ __align__(16) float xin_s[2][128];

  const int tid  = threadIdx.x;
  const int w    = tid >> 6;
  const int lane = tid & 63;
  const int q15  = lane & 15;
  const int g    = lane >> 4;
  const int b0   = blockIdx.x * BB;
  const bool gA  = (w < 4);
  const int r0c  = 16*(w & 3) + 4*g;
  const int f0   = 16*w + 4*g;
  const int c01  = q15 & 1;

  const int aWH = (w>>1)*128 + (2*(w&1) + (g>>1))*32 + q15*8 + 4*(g&1);
  const int aRD = g*32 + (q15 & 3)*8;
  const int bWH = ((w&3)>>1)*512 + ((2*(w&3) + (g>>1)) & 3)*128 + q15*8 + 4*(g&1);
  const int bRD = g*128 + q15*8;

  const f32x4 vz = {0.f, 0.f, 0.f, 0.f};
  const bf16x8 z8 = {0,0,0,0,0,0,0,0};

  // ---- weight fragments ----
  bf16x8 w1h[10], w1l[10];
#pragma unroll
  for (int jt = 0; jt < 10; ++jt)
    load_wfrag(W1 + (size_t)(16*w + q15)*KH + jt*32 + 8*g, w1h[jt], w1l[jt]);

  bf16x8 wxh[6], wxl[6];
#pragma unroll
  for (int i = 0; i < 6; ++i) { wxh[i] = z8; wxl[i] = z8; }
  f32x4 biasv = vz, b2r = vz;
  f32x4 b1r = *(const f32x4*)(b1 + f0);
  if (gA) {
#pragma unroll
    for (int kt = 0; kt < 2; ++kt)
      load_wfrag(W_hh + (size_t)(16*w + q15)*HID + kt*32 + 8*g, wxh[kt], wxl[kt]);
#pragma unroll
    for (int kt = 0; kt < 4; ++kt)
      load_wfrag(W2 + (size_t)(16*w + q15)*FEAT + kt*32 + 8*g, wxh[2+kt], wxl[2+kt]);
    b2r = *(const f32x4*)(b2 + r0c);
  } else {
#pragma unroll
    for (int kt = 0; kt < 2; ++kt)
      load_wfrag(W_in + (size_t)(16*(w-4) + q15)*INPD + kt*32 + 8*g, wxh[kt], wxl[kt]);
    biasv = *(const f32x4*)(b_in + r0c) + *(const f32x4*)(b_hh + r0c);
  }

  for (int i = tid; i < 512; i += NTHR) ((unsigned*)B1lds)[i] = 0u;
  __syncthreads();

  // ---- state init ----
  f32x4 hprev = vz;
  float4 xc0, xc1, xc2, xc3;
  if (gA) {
    if (q15 < 2) {
      hprev = *(const f32x4*)(h0g + (size_t)(b0 + q15)*HID + r0c);
      unsigned n0, n1, n2, n3;
      pack4(hprev.x, hprev.y, hprev.z, hprev.w, n0, n1, n2, n3);
      *(uint2*)&B1lds[bWH]      = make_uint2(n0, n1);
      *(uint2*)&B1lds[bWH + 16] = make_uint2(n2, n3);
    }
  } else {
    // xin for t=0 -> xin_s[0]
    const float* xp = x + (size_t)(b0 + c01)*INPD + 8*g;
    float4 v0 = *(const float4*)xp;        float4 v1 = *(const float4*)(xp + 4);
    float4 v2 = *(const float4*)(xp + 32); float4 v3 = *(const float4*)(xp + 36);
    bf16x8 th0, tl0, th1, tl1;
    pack_frag(v0, v1, th0, tl0);
    pack_frag(v2, v3, th1, tl1);
    bf16x8 f0b = (q15 & 2) ? tl0 : th0;
    bf16x8 f1b = (q15 & 2) ? tl1 : th1;
    f32x4 aHx = vz, aLx = vz;
    aHx = MFMA(wxh[0], f0b, aHx); aHx = MFMA(wxh[1], f1b, aHx);
    aLx = MFMA(wxl[0], f0b, aLx); aLx = MFMA(wxl[1], f1b, aLx);
    f32x4 xi = fold2(aHx + aLx) + biasv;
    if (q15 < 2) *(f32x4*)&xin_s[0][q15*64 + r0c] = xi;
    // preload raw x[1]
    const float* xq = x + (size_t)1*BATCH*INPD + (size_t)(b0 + c01)*INPD + 8*g;
    xc0 = *(const float4*)xq;        xc1 = *(const float4*)(xq + 4);
    xc2 = *(const float4*)(xq + 32); xc3 = *(const float4*)(xq + 36);
  }

  bf16x8 rb[KEEP][2];
#pragma unroll
  for (int s = 0; s < KEEP; ++s) { rb[s][0] = z8; rb[s][1] = z8; }

  // carried MLP1 acc: at P1(t) it holds ranks 0-3 of step t (zero for t=0)
  f32x4 accH = vz, accL = vz;
  __syncthreads();

  int t5 = 0;
  auto step = [&](auto pc) {
    constexpr int ph = decltype(pc)::v;
    constexpr int sN = (ph + 4) % 5;   // h(t-1)
    constexpr int s3 = (ph + 3) % 5;   // h(t-2) -> r2 of step t+1
    constexpr int s2 = (ph + 2) % 5;   // h(t-3) -> r1 of step t+1
    constexpr int s1 = (ph + 1) % 5;   // h(t-4) -> r0 of step t+1
    const int t = t5 + ph;

    // ---- P1 ----
    rb[sN][0] = *(const bf16x8*)&B1lds[bRD];
    rb[sN][1] = *(const bf16x8*)&B1lds[bRD + 512];
    f32x4 xinv = vz;
    if (gA) xinv = *(const f32x4*)&xin_s[t & 1][(q15 & 1)*64 + r0c];

    // publish path: newest pair, split chain (tH/tL seeded from zero)
    f32x4 tH = MFMA(w1h[9], rb[sN][1], vz);
    f32x4 tL = MFMA(w1l[9], rb[sN][1], vz);
    accH = MFMA(w1h[8], rb[sN][0], accH);
    accL = MFMA(w1l[8], rb[sN][0], accL);
    {
      f32x4 apre = fold2((accH + tH) + (accL + tL)) + b1r;
      f32x4 av = __builtin_elementwise_max(apre, vz);
      unsigned p0, p1, p2, p3;
      pack4(av.x, av.y, av.z, av.w, p0, p1, p2, p3);
      if (q15 < 2) {
        *(uint2*)&a_s[aWH]      = make_uint2(p0, p1);
        *(uint2*)&a_s[aWH + 16] = make_uint2(p2, p3);
      }
    }

    f32x4 hobs = vz;
    if (gA) {
      // RNN + hobs (parallel to publish path)
      f32x4 rH = MFMA(wxh[0], rb[sN][0], vz);
      f32x4 rL = MFMA(wxl[0], rb[sN][0], vz);
      rH = MFMA(wxh[1], rb[sN][1], rH);
      rL = MFMA(wxl[1], rb[sN][1], rL);
      f32x4 pre = fold2(rH + rL) + xinv;           // xin includes biases
      f32x4 rl_ = __builtin_elementwise_max(pre, vz);
      hobs = hprev * (1.f - ALPHA) + rl_ * ALPHA;
    }

    // start acc for step t+1: ranks 2,3 (register ring; r3 = just-read rb[sN])
    accH = MFMA(w1h[4], rb[s3][0], vz);
    accL = MFMA(w1l[4], rb[s3][0], vz);
    accH = MFMA(w1h[5], rb[s3][1], accH);
    accL = MFMA(w1l[5], rb[s3][1], accL);
    accH = MFMA(w1h[6], rb[sN][0], accH);
    accL = MFMA(w1l[6], rb[sN][0], accL);
    accH = MFMA(w1h[7], rb[sN][1], accH);
    accL = MFMA(w1l[7], rb[sN][1], accL);
    barrier_fast();   // bar A: a_s ready

    // ---- P2 ----
    if (gA) {
      bf16x8 af0 = *(const bf16x8*)&a_s[aRD +   0];
      bf16x8 af1 = *(const bf16x8*)&a_s[aRD + 128];
      bf16x8 af2 = *(const bf16x8*)&a_s[aRD + 256];
      bf16x8 af3 = *(const bf16x8*)&a_s[aRD + 384];
      // acc(t+1) += ranks 0,1 (independent of a_s; hides its read latency)
      accH = MFMA(w1h[0], rb[s1][0], accH);
      accL = MFMA(w1l[0], rb[s1][0], accL);
      accH = MFMA(w1h[1], rb[s1][1], accH);
      accL = MFMA(w1l[1], rb[s1][1], accL);
      accH = MFMA(w1h[2], rb[s2][0], accH);
      accL = MFMA(w1l[2], rb[s2][0], accL);
      accH = MFMA(w1h[3], rb[s2][1], accH);
      accL = MFMA(w1l[3], rb[s2][1], accL);
      // MLP2: two 2-deep chains per H/L
      f32x4 mH0 = MFMA(wxh[2], af0, vz);
      f32x4 mL0 = MFMA(wxl[2], af0, vz);
      f32x4 mH1 = MFMA(wxh[4], af2, vz);
      f32x4 mL1 = MFMA(wxl[4], af2, vz);
      mH0 = MFMA(wxh[3], af1, mH0);
      mL0 = MFMA(wxl[3], af1, mL0);
      mH1 = MFMA(wxh[5], af3, mH1);
      mL1 = MFMA(wxl[5], af3, mL1);
      f32x4 hm = fold2((mH0 + mH1) + (mL0 + mL1)) + b2r;
      f32x4 hn = (t >= KEEP) ? (hobs + hm) * 0.5f : hobs;
      if (q15 < 2) {
        *(f32x4*)(io + (size_t)t*BATCH*HID + (size_t)(b0 + q15)*HID + r0c) = hn;
        if (t == TSTEPS-1)
          *(f32x4*)(io + (size_t)TSTEPS*BATCH*HID + (size_t)(b0 + q15)*HID + r0c) = hn;
        unsigned n0, n1, n2, n3;
        pack4(hn.x, hn.y, hn.z, hn.w, n0, n1, n2, n3);
        *(uint2*)&B1lds[bWH]      = make_uint2(n0, n1);
        *(uint2*)&B1lds[bWH + 16] = make_uint2(n2, n3);
      }
      hprev = hn;
    } else {
      // issue raw x[t+2] (consumed at P2(t+1))
      float4 xn0, xn1, xn2, xn3;
      {
        int tn = t + 2; if (tn > TSTEPS-1) tn = TSTEPS-1;
        const float* xp = x + (size_t)tn*BATCH*INPD + (size_t)(b0 + c01)*INPD + 8*g;
        xn0 = *(const float4*)xp;        xn1 = *(const float4*)(xp + 4);
        xn2 = *(const float4*)(xp + 32); xn3 = *(const float4*)(xp + 36);
      }
      // acc(t+1) += ranks 0,1
      accH = MFMA(w1h[0], rb[s1][0], accH);
      accL = MFMA(w1l[0], rb[s1][0], accL);
      accH = MFMA(w1h[1], rb[s1][1], accH);
      accL = MFMA(w1l[1], rb[s1][1], accL);
      accH = MFMA(w1h[2], rb[s2][0], accH);
      accL = MFMA(w1l[2], rb[s2][0], accL);
      accH = MFMA(w1h[3], rb[s2][1], accH);
      accL = MFMA(w1l[3], rb[s2][1], accL);
      // x-stage: pack x[t+1] (loaded last step), XIN -> xin_s[(t+1)&1]
      bf16x8 th0, tl0, th1, tl1;
      pack_frag(xc0, xc1, th0, tl0);
      pack_frag(xc2, xc3, th1, tl1);
      bf16x8 f0b = (q15 & 2) ? tl0 : th0;
      bf16x8 f1b = (q15 & 2) ? tl1 : th1;
      f32x4 xH = MFMA(wxh[0], f0b, vz);
      f32x4 xL = MFMA(wxl[0], f0b, vz);
      xH = MFMA(wxh[1], f1b, xH);
      xL = MFMA(wxl[1], f1b, xL);
      f32x4 xi = fold2(xH + xL) + biasv;
      if (q15 < 2) *(f32x4*)&xin_s[(t + 1) & 1][q15*64 + r0c] = xi;
      xc0 = xn0; xc1 = xn1; xc2 = xn2; xc3 = xn3;
    }
    barrier_fast();   // bar B: B1lds + xin_s staged
  };

  for (t5 = 0; t5 < TSTEPS; t5 += 5) {
    step(IC<0>{});
    step(IC<1>{});
    step(IC<2>{});
    step(IC<3>{});
    step(IC<4>{});
  }
}

extern "C" void kernel_launch(void* const* d_in, const int* in_sizes, int n_in,
                              void* d_out, int out_size, void* d_ws, size_t ws_size,
                              hipStream_t stream) {
  (void)in_sizes; (void)n_in; (void)out_size; (void)d_ws; (void)ws_size;
  const float* x    = (const float*)d_in[0];
  const float* h0   = (const float*)d_in[1];
  const float* W_in = (const float*)d_in[2];
  const float* b_in = (const float*)d_in[3];
  const float* W_hh = (const float*)d_in[4];
  const float* b_hh = (const float*)d_in[5];
  const float* W1   = (const float*)d_in[6];
  const float* b1   = (const float*)d_in[7];
  const float* W2   = (const float*)d_in[8];
  const float* b2   = (const float*)d_in[9];
  float* out = (float*)d_out;

  seq_kernel<<<NBLK, NTHR, 0, stream>>>(x, out, h0, W_in, b_in, W_hh, b_hh, W1, b1, W2, b2);
}

// Round 14
// 926.667 us; speedup vs baseline: 1.0833x; 1.0833x over previous
//
#include <hip/hip_runtime.h>

typedef short bf16x8 __attribute__((ext_vector_type(8)));
typedef float f32x4  __attribute__((ext_vector_type(4)));

#define TSTEPS 1000
#define BATCH  512
#define HID    64
#define INPD   64
#define FEAT   128
#define KEEP   5
#define KH     320
#define ALPHA  0.2f
#define BB     2
#define NBLK   (BATCH/BB)   // 256
#define NTHR   512

#define MFMA(a,b,c) __builtin_amdgcn_mfma_f32_16x16x32_bf16(a, b, c, 0, 0, 0)

template<int P> struct IC { static constexpr int v = P; };

// Raw barrier: flush own LDS writes, sync. No vmcnt drain.
__device__ __forceinline__ void barrier_fast() {
  asm volatile("s_waitcnt lgkmcnt(0)" ::: "memory");
  __builtin_amdgcn_s_barrier();
  asm volatile("" ::: "memory");
}

// lane <-> lane^2 exchange via DPP quad_perm [2,3,0,1] (VALU, not LDS pipe)
__device__ __forceinline__ float qx2(float v) {
  return __uint_as_float((unsigned)__builtin_amdgcn_update_dpp(
      0, (int)__float_as_uint(v), 0x4E /*quad_perm[2,3,0,1]*/, 0xF, 0xF, true));
}
// hi/lo column fold: cols (0,1)=hi products, (2,3)=lo products; total = v + v[lane^2]
__device__ __forceinline__ f32x4 fold2(f32x4 v) {
  f32x4 r;
  r.x = v.x + qx2(v.x);
  r.y = v.y + qx2(v.y);
  r.z = v.z + qx2(v.z);
  r.w = v.w + qx2(v.w);
  return r;
}

// split 4 f32 into bf16-hi (truncated) and bf16-lo (rounded residual), packed 2-per-u32
__device__ __forceinline__ void pack4(float x0, float x1, float x2, float x3,
                                      unsigned &h0, unsigned &h1,
                                      unsigned &l0, unsigned &l1) {
  unsigned a0 = __float_as_uint(x0), a1 = __float_as_uint(x1);
  unsigned a2 = __float_as_uint(x2), a3 = __float_as_uint(x3);
  h0 = __builtin_amdgcn_perm(a1, a0, 0x07060302u);
  h1 = __builtin_amdgcn_perm(a3, a2, 0x07060302u);
  float r0 = x0 - __uint_as_float(a0 & 0xFFFF0000u);
  float r1 = x1 - __uint_as_float(a1 & 0xFFFF0000u);
  float r2 = x2 - __uint_as_float(a2 & 0xFFFF0000u);
  float r3 = x3 - __uint_as_float(a3 & 0xFFFF0000u);
  asm("v_cvt_pk_bf16_f32 %0, %1, %2" : "=v"(l0) : "v"(r0), "v"(r1));
  asm("v_cvt_pk_bf16_f32 %0, %1, %2" : "=v"(l1) : "v"(r2), "v"(r3));
}

__device__ __forceinline__ void pack_frag(float4 v0, float4 v1, bf16x8 &hi, bf16x8 &lo) {
  int4 h4, l4;
  pack4(v0.x, v0.y, v0.z, v0.w, (unsigned&)h4.x, (unsigned&)h4.y, (unsigned&)l4.x, (unsigned&)l4.y);
  pack4(v1.x, v1.y, v1.z, v1.w, (unsigned&)h4.z, (unsigned&)h4.w, (unsigned&)l4.z, (unsigned&)l4.w);
  hi = __builtin_bit_cast(bf16x8, h4);
  lo = __builtin_bit_cast(bf16x8, l4);
}

__device__ __forceinline__ void load_wfrag(const float* p, bf16x8 &hi, bf16x8 &lo) {
  float4 v0 = *(const float4*)p;
  float4 v1 = *(const float4*)(p + 4);
  pack_frag(v0, v1, hi, lo);
}

// ---------------- packed-column MFMA kernel (r12 structure + chain splits + ptr incr) ----------------
// P1 (all): read h-frag; publish a(t): carried acc + depth-1 newest pair; -> a_s.   bar A
// P2: gA: acc(t+1) r0-3 (two 4-deep chains); RNN; MLP2 (4x 2-deep); hn; io; stage B1lds
//     gB: acc(t+1) r0-3; issue x[t+2]; pack x[t+1]; XIN -> xin_s[(t+1)&1]           bar B
__global__ __launch_bounds__(NTHR, 2) void seq_kernel(
    const float* __restrict__ x,    float* __restrict__ io,
    const float* __restrict__ h0g,
    const float* __restrict__ W_in, const float* __restrict__ b_in,
    const float* __restrict__ W_hh, const float* __restrict__ b_hh,
    const float* __restrict__ W1,   const float* __restrict__ b1,
    const float* __restrict__ W2,   const float* __restrict__ b2) {

  __shared__ __align__(16) short B1lds[1024];
  __shared__ __align__(16) short a_s[512];
  __shared__ __align__(16) float xin_s[2][128];

  const int tid  = threadIdx.x;
  const int w    = tid >> 6;
  const int lane = tid & 63;
  const int q15  = lane & 15;
  const int g    = lane >> 4;
  const int b0   = blockIdx.x * BB;
  const bool gA  = (w < 4);
  const int r0c  = 16*(w & 3) + 4*g;
  const int f0   = 16*w + 4*g;
  const int c01  = q15 & 1;

  const int aWH = (w>>1)*128 + (2*(w&1) + (g>>1))*32 + q15*8 + 4*(g&1);
  const int aRD = g*32 + (q15 & 3)*8;
  const int bWH = ((w&3)>>1)*512 + ((2*(w&3) + (g>>1)) & 3)*128 + q15*8 + 4*(g&1);
  const int bRD = g*128 + q15*8;

  const f32x4 vz = {0.f, 0.f, 0.f, 0.f};
  const bf16x8 z8 = {0,0,0,0,0,0,0,0};

  // ---- weight fragments ----
  bf16x8 w1h[10], w1l[10];
#pragma unroll
  for (int jt = 0; jt < 10; ++jt)
    load_wfrag(W1 + (size_t)(16*w + q15)*KH + jt*32 + 8*g, w1h[jt], w1l[jt]);

  bf16x8 wxh[6], wxl[6];
#pragma unroll
  for (int i = 0; i < 6; ++i) { wxh[i] = z8; wxl[i] = z8; }
  f32x4 biasv = vz, b2r = vz;
  f32x4 b1r = *(const f32x4*)(b1 + f0);
  if (gA) {
#pragma unroll
    for (int kt = 0; kt < 2; ++kt)
      load_wfrag(W_hh + (size_t)(16*w + q15)*HID + kt*32 + 8*g, wxh[kt], wxl[kt]);
#pragma unroll
    for (int kt = 0; kt < 4; ++kt)
      load_wfrag(W2 + (size_t)(16*w + q15)*FEAT + kt*32 + 8*g, wxh[2+kt], wxl[2+kt]);
    b2r = *(const f32x4*)(b2 + r0c);
  } else {
#pragma unroll
    for (int kt = 0; kt < 2; ++kt)
      load_wfrag(W_in + (size_t)(16*(w-4) + q15)*INPD + kt*32 + 8*g, wxh[kt], wxl[kt]);
    biasv = *(const f32x4*)(b_in + r0c) + *(const f32x4*)(b_hh + r0c);
  }

  for (int i = tid; i < 512; i += NTHR) ((unsigned*)B1lds)[i] = 0u;
  __syncthreads();

  // ---- incremental pointers ----
  float* ioP = io + (size_t)(b0 + q15)*HID + r0c;                       // row t, advances
  float* ioF = io + (size_t)TSTEPS*BATCH*HID + (size_t)(b0 + q15)*HID + r0c;  // hT row
  const float* xP = x + (size_t)2*BATCH*INPD + (size_t)(b0 + c01)*INPD + 8*g; // row t+2

  // ---- state init ----
  f32x4 hprev = vz;
  float4 xc0, xc1, xc2, xc3;            // raw x[t+1] (gB)
  if (gA) {
    if (q15 < 2) {
      hprev = *(const f32x4*)(h0g + (size_t)(b0 + q15)*HID + r0c);
      unsigned n0, n1, n2, n3;
      pack4(hprev.x, hprev.y, hprev.z, hprev.w, n0, n1, n2, n3);
      *(uint2*)&B1lds[bWH]      = make_uint2(n0, n1);
      *(uint2*)&B1lds[bWH + 16] = make_uint2(n2, n3);
    }
  } else {
    // xin for t=0 -> xin_s[0]
    const float* xp0 = x + (size_t)(b0 + c01)*INPD + 8*g;
    float4 v0 = *(const float4*)xp0;        float4 v1 = *(const float4*)(xp0 + 4);
    float4 v2 = *(const float4*)(xp0 + 32); float4 v3 = *(const float4*)(xp0 + 36);
    bf16x8 th0, tl0, th1, tl1;
    pack_frag(v0, v1, th0, tl0);
    pack_frag(v2, v3, th1, tl1);
    bf16x8 f0b = (q15 & 2) ? tl0 : th0;
    bf16x8 f1b = (q15 & 2) ? tl1 : th1;
    f32x4 aHx = MFMA(wxh[0], f0b, vz);
    f32x4 aLx = MFMA(wxl[0], f0b, vz);
    aHx = MFMA(wxh[1], f1b, aHx);
    aLx = MFMA(wxl[1], f1b, aLx);
    f32x4 xi = fold2(aHx + aLx) + biasv;
    if (q15 < 2) *(f32x4*)&xin_s[0][q15*64 + r0c] = xi;
    // preload raw x[1]
    const float* xq = x + (size_t)1*BATCH*INPD + (size_t)(b0 + c01)*INPD + 8*g;
    xc0 = *(const float4*)xq;        xc1 = *(const float4*)(xq + 4);
    xc2 = *(const float4*)(xq + 32); xc3 = *(const float4*)(xq + 36);
  }

  bf16x8 rb[KEEP][2];
#pragma unroll
  for (int s = 0; s < KEEP; ++s) { rb[s][0] = z8; rb[s][1] = z8; }

  // carried MLP1 acc: at P1(t) holds ranks 0-3 of step t (zero for t=0)
  f32x4 accH = vz, accL = vz;
  __syncthreads();

  int t5 = 0;
  auto step = [&](auto pc) {
    constexpr int ph = decltype(pc)::v;
    constexpr int sN = (ph + 4) % 5;   // h(t-1)
    constexpr int s1 = (ph + 1) % 5;   // r0 of step t+1
    constexpr int s2 = (ph + 2) % 5;   // r1 of step t+1
    constexpr int s3 = (ph + 3) % 5;   // r2 of step t+1
    const int t = t5 + ph;

    // ---- P1 (short): newest-slot MLP1 (split depth-1) + publish a_s ----
    rb[sN][0] = *(const bf16x8*)&B1lds[bRD];
    rb[sN][1] = *(const bf16x8*)&B1lds[bRD + 512];

    f32x4 tH = MFMA(w1h[9], rb[sN][1], vz);
    f32x4 tL = MFMA(w1l[9], rb[sN][1], vz);
    accH = MFMA(w1h[8], rb[sN][0], accH);
    accL = MFMA(w1l[8], rb[sN][0], accL);
    {
      f32x4 apre = fold2((accH + tH) + (accL + tL)) + b1r;
      f32x4 av = __builtin_elementwise_max(apre, vz);
      unsigned p0, p1, p2, p3;
      pack4(av.x, av.y, av.z, av.w, p0, p1, p2, p3);
      if (q15 < 2) {
        *(uint2*)&a_s[aWH]      = make_uint2(p0, p1);
        *(uint2*)&a_s[aWH + 16] = make_uint2(p2, p3);
      }
    }
    barrier_fast();   // bar A: a_s ready

    // ---- P2 ----
    // acc(t+1) ranks 0-3: two 4-deep chains (merged at phase end)
    f32x4 nHa, nHb, nLa, nLb;
    if (gA) {
      bf16x8 af0 = *(const bf16x8*)&a_s[aRD +   0];
      bf16x8 af1 = *(const bf16x8*)&a_s[aRD + 128];
      bf16x8 af2 = *(const bf16x8*)&a_s[aRD + 256];
      bf16x8 af3 = *(const bf16x8*)&a_s[aRD + 384];
      f32x4 xinv = *(const f32x4*)&xin_s[t & 1][(q15 & 1)*64 + r0c];
      // independent of a_s -> hides its read latency
      nHa = MFMA(w1h[0], rb[s1][0], vz);
      nLa = MFMA(w1l[0], rb[s1][0], vz);
      nHb = MFMA(w1h[2], rb[s2][0], vz);
      nLb = MFMA(w1l[2], rb[s2][0], vz);
      nHa = MFMA(w1h[1], rb[s1][1], nHa);
      nLa = MFMA(w1l[1], rb[s1][1], nLa);
      nHb = MFMA(w1h[3], rb[s2][1], nHb);
      nLb = MFMA(w1l[3], rb[s2][1], nLb);
      nHa = MFMA(w1h[4], rb[s3][0], nHa);
      nLa = MFMA(w1l[4], rb[s3][0], nLa);
      nHb = MFMA(w1h[6], rb[sN][0], nHb);
      nLb = MFMA(w1l[6], rb[sN][0], nLb);
      nHa = MFMA(w1h[5], rb[s3][1], nHa);
      nLa = MFMA(w1l[5], rb[s3][1], nLa);
      nHb = MFMA(w1h[7], rb[sN][1], nHb);
      nLb = MFMA(w1l[7], rb[sN][1], nLb);
      // RNN (depth-1 pairs)
      f32x4 rH0 = MFMA(wxh[0], rb[sN][0], vz);
      f32x4 rL0 = MFMA(wxl[0], rb[sN][0], vz);
      f32x4 rH1 = MFMA(wxh[1], rb[sN][1], vz);
      f32x4 rL1 = MFMA(wxl[1], rb[sN][1], vz);
      // MLP2: four 2-deep chains
      f32x4 mH0 = MFMA(wxh[2], af0, vz);
      f32x4 mL0 = MFMA(wxl[2], af0, vz);
      f32x4 mH1 = MFMA(wxh[4], af2, vz);
      f32x4 mL1 = MFMA(wxl[4], af2, vz);
      mH0 = MFMA(wxh[3], af1, mH0);
      mL0 = MFMA(wxl[3], af1, mL0);
      mH1 = MFMA(wxh[5], af3, mH1);
      mL1 = MFMA(wxl[5], af3, mL1);
      f32x4 pre = fold2((rH0 + rH1) + (rL0 + rL1)) + xinv;   // xin includes biases
      f32x4 rl_ = __builtin_elementwise_max(pre, vz);
      f32x4 hobs = hprev * (1.f - ALPHA) + rl_ * ALPHA;
      f32x4 hm = fold2((mH0 + mH1) + (mL0 + mL1)) + b2r;
      f32x4 hn = (t >= KEEP) ? (hobs + hm) * 0.5f : hobs;
      if (q15 < 2) {
        *(f32x4*)ioP = hn;
        if (t == TSTEPS-1) *(f32x4*)ioF = hn;
        unsigned n0, n1, n2, n3;
        pack4(hn.x, hn.y, hn.z, hn.w, n0, n1, n2, n3);
        *(uint2*)&B1lds[bWH]      = make_uint2(n0, n1);
        *(uint2*)&B1lds[bWH + 16] = make_uint2(n2, n3);
      }
      hprev = hn;
    } else {
      // issue raw x[t+2] (consumed at P2(t+1))
      float4 xn0 = *(const float4*)xP;        float4 xn1 = *(const float4*)(xP + 4);
      float4 xn2 = *(const float4*)(xP + 32); float4 xn3 = *(const float4*)(xP + 36);
      // acc(t+1) ranks 0-3 (two 4-deep chains)
      nHa = MFMA(w1h[0], rb[s1][0], vz);
      nLa = MFMA(w1l[0], rb[s1][0], vz);
      nHb = MFMA(w1h[2], rb[s2][0], vz);
      nLb = MFMA(w1l[2], rb[s2][0], vz);
      nHa = MFMA(w1h[1], rb[s1][1], nHa);
      nLa = MFMA(w1l[1], rb[s1][1], nLa);
      nHb = MFMA(w1h[3], rb[s2][1], nHb);
      nLb = MFMA(w1l[3], rb[s2][1], nLb);
      nHa = MFMA(w1h[4], rb[s3][0], nHa);
      nLa = MFMA(w1l[4], rb[s3][0], nLa);
      nHb = MFMA(w1h[6], rb[sN][0], nHb);
      nLb = MFMA(w1l[6], rb[sN][0], nLb);
      nHa = MFMA(w1h[5], rb[s3][1], nHa);
      nLa = MFMA(w1l[5], rb[s3][1], nLa);
      nHb = MFMA(w1h[7], rb[sN][1], nHb);
      nLb = MFMA(w1l[7], rb[sN][1], nLb);
      // x-stage: pack x[t+1], XIN (depth-1 pairs) -> xin_s[(t+1)&1]
      bf16x8 th0, tl0, th1, tl1;
      pack_frag(xc0, xc1, th0, tl0);
      pack_frag(xc2, xc3, th1, tl1);
      bf16x8 f0b = (q15 & 2) ? tl0 : th0;
      bf16x8 f1b = (q15 & 2) ? tl1 : th1;
      f32x4 xH0 = MFMA(wxh[0], f0b, vz);
      f32x4 xL0 = MFMA(wxl[0], f0b, vz);
      f32x4 xH1 = MFMA(wxh[1], f1b, vz);
      f32x4 xL1 = MFMA(wxl[1], f1b, vz);
      f32x4 xi = fold2((xH0 + xH1) + (xL0 + xL1)) + biasv;
      if (q15 < 2) *(f32x4*)&xin_s[(t + 1) & 1][q15*64 + r0c] = xi;
      xc0 = xn0; xc1 = xn1; xc2 = xn2; xc3 = xn3;
      if (t < TSTEPS-3) xP += BATCH*INPD;   // clamp at row TSTEPS-1
    }
    accH = nHa + nHb;
    accL = nLa + nLb;
    ioP += BATCH*HID;
    barrier_fast();   // bar B: B1lds + xin_s staged
  };

  for (t5 = 0; t5 < TSTEPS; t5 += 5) {
    step(IC<0>{});
    step(IC<1>{});
    step(IC<2>{});
    step(IC<3>{});
    step(IC<4>{});
  }
}

extern "C" void kernel_launch(void* const* d_in, const int* in_sizes, int n_in,
                              void* d_out, int out_size, void* d_ws, size_t ws_size,
                              hipStream_t stream) {
  (void)in_sizes; (void)n_in; (void)out_size; (void)d_ws; (void)ws_size;
  const float* x    = (const float*)d_in[0];
  const float* h0   = (const float*)d_in[1];
  const float* W_in = (const float*)d_in[2];
  const float* b_in = (const float*)d_in[3];
  const float* W_hh = (const float*)d_in[4];
  const float* b_hh = (const float*)d_in[5];
  const float* W1   = (const float*)d_in[6];
  const float* b1   = (const float*)d_in[7];
  const float* W2   = (const float*)d_in[8];
  const float* b2   = (const float*)d_in[9];
  float* out = (float*)d_out;

  seq_kernel<<<NBLK, NTHR, 0, stream>>>(x, out, h0, W_in, b_in, W_hh, b_hh, W1, b1, W2, b2);
}